// Round 19
// baseline (144.654 us; speedup 1.0000x reference)
//
#include <hip/hip_runtime.h>
#include <hip/hip_bf16.h>
#include <math.h>

#define S_LEN 2048
#define HID 2048
#define NH 32
#define NKV 8
#define HD 64
#define WINDOW 1024
#define QBLK 128
#define QKVN 3072   // fused Q(2048) | K(512) | V(512) columns

typedef __attribute__((ext_vector_type(8))) short bx8;          // 8 bf16 (4 VGPRs) — MFMA A/B frag
typedef __attribute__((ext_vector_type(4))) float fx4;          // MFMA C/D frag
typedef __attribute__((ext_vector_type(8))) unsigned short us8; // 8 bf16 raw

#define GL_LDS16(gp, lp) \
    __builtin_amdgcn_global_load_lds((__attribute__((address_space(1))) const void*)(gp), \
                                     (__attribute__((address_space(3))) void*)(lp), 16, 0, 0)

// Packed layouts (swizzle baked in; LDS image identical to previous rounds):
//   A (hsb):  tile (mt,kt) = 64rows x 32k, elem off = (mt*64+kt)*2048 + r*32 + s*8 + ko,
//             s = chunk ^ ((r>>1)&3), chunk = (k&31)>>3, ko = k&7
//   B (WqkvT/WoT): tile (nt,kt) = 128rows x 32k, elem off = (nt*64+kt)*4096 + r*32 + s*8 + ko

// ---------------- prep: rope tables + hs conv(packed) + weight transposes(packed), ONE dispatch ----------------
__global__ __launch_bounds__(256) void prep_kernel(const float* __restrict__ hs,
                                                   const float* __restrict__ Wq,
                                                   const float* __restrict__ Wk,
                                                   const float* __restrict__ Wv,
                                                   const float* __restrict__ Wo,
                                                   float* __restrict__ cosT, float* __restrict__ sinT,
                                                   __hip_bfloat16* __restrict__ hsb,
                                                   __hip_bfloat16* __restrict__ WqkvT,
                                                   __hip_bfloat16* __restrict__ WoT) {
    __shared__ float tile[32][33];
    int b = blockIdx.x, t = threadIdx.x;
    if (b < 256) {
        int idx = b * 256 + t;           // s*32 + f
        int s = idx >> 5, f = idx & 31;
        double inv = exp(-2.0 * (double)f / 64.0 * log(500000.0));
        double ang = (double)s * inv;
        cosT[idx] = (float)cos(ang);
        sinT[idx] = (float)sin(ang);
        return;
    }
    b -= 256;
    if (b < 2048) {
        int i = (b * 256 + t) * 8;
        int m = i >> 11, k0 = i & 2047;                 // 8 consecutive k, one chunk
        float4 a = *reinterpret_cast<const float4*>(&hs[i]);
        float4 c = *reinterpret_cast<const float4*>(&hs[i + 4]);
        __hip_bfloat16 o[8] __attribute__((aligned(16)));
        o[0] = __float2bfloat16(a.x); o[1] = __float2bfloat16(a.y);
        o[2] = __float2bfloat16(a.z); o[3] = __float2bfloat16(a.w);
        o[4] = __float2bfloat16(c.x); o[5] = __float2bfloat16(c.y);
        o[6] = __float2bfloat16(c.z); o[7] = __float2bfloat16(c.w);
        int mt = m >> 6, r = m & 63, kt = k0 >> 5;
        int s2 = ((k0 & 31) >> 3) ^ ((r >> 1) & 3);
        size_t dst = (size_t)(mt * 64 + kt) * 2048 + r * 32 + s2 * 8;
        *reinterpret_cast<bx8*>(&hsb[dst]) = *reinterpret_cast<bx8*>(o);
        return;
    }
    b -= 2048;
    const float* src; __hip_bfloat16* dst; int Nd, bx, by, gbase;
    if (b < 4096)      { src = Wq; dst = WqkvT; Nd = 2048; bx = b & 63; by = b >> 6; gbase = 0; }
    else if (b < 5120) { b -= 4096; src = Wk; dst = WqkvT; Nd = 512; bx = b & 15; by = b >> 4; gbase = 2048; }
    else if (b < 6144) { b -= 5120; src = Wv; dst = WqkvT; Nd = 512; bx = b & 15; by = b >> 4; gbase = 2560; }
    else               { b -= 6144; src = Wo; dst = WoT;   Nd = 2048; bx = b & 63; by = b >> 6; gbase = 0; }
    int n0 = bx * 32, k0 = by * 32, tx = t & 31, ty = t >> 5;  // 32 x 8
#pragma unroll
    for (int i = 0; i < 4; i++)
        tile[ty + 8 * i][tx] = src[(size_t)(k0 + ty + 8 * i) * Nd + n0 + tx];
    __syncthreads();
    const int kt = k0 >> 5, chunk = tx >> 3, ko = tx & 7;
#pragma unroll
    for (int i = 0; i < 4; i++) {
        int gn = gbase + n0 + ty + 8 * i;
        int nt = gn >> 7, r = gn & 127;
        int s2 = chunk ^ ((r >> 1) & 3);
        dst[(size_t)(nt * 64 + kt) * 4096 + r * 32 + s2 * 8 + ko] =
            __float2bfloat16(tile[tx][ty + 8 * i]);
    }
}

// ---------------- rope (Q+K) + vtrans, ONE dispatch (frozen) ----------------
__global__ __launch_bounds__(256) void ropev_kernel(__hip_bfloat16* __restrict__ QKV,
                                                    __hip_bfloat16* __restrict__ Vt,
                                                    const float* __restrict__ cosT,
                                                    const float* __restrict__ sinT) {
    __shared__ __hip_bfloat16 tile[32][33];
    int b = blockIdx.x, t = threadIdx.x;
    if (b < 10240) {
        int idx = b * 256 + t;           // s*(40*32) + head*32 + f
        int f = idx & 31;
        int head = (idx >> 5) % (NH + NKV);
        int s = idx / ((NH + NKV) * 32);
        float c  = cosT[(s << 5) + f];
        float sn = sinT[(s << 5) + f];
        __hip_bfloat16* p = (head < NH) ? (QKV + (size_t)s * QKVN + head * HD)
                                        : (QKV + (size_t)s * QKVN + 2048 + (head - NH) * HD);
        float x1 = __bfloat162float(p[f]), x2 = __bfloat162float(p[f + 32]);
        p[f]      = __float2bfloat16(x1 * c - x2 * sn);
        p[f + 32] = __float2bfloat16(x2 * c + x1 * sn);
        return;
    }
    b -= 10240;
    int s0 = (b & 63) * 32, d0 = (b >> 6) * 32;
    int tx = t & 31, ty = t >> 5;  // 32 x 8
#pragma unroll
    for (int i = 0; i < 4; i++)
        tile[ty + 8 * i][tx] = QKV[(size_t)(s0 + ty + 8 * i) * QKVN + 2560 + d0 + tx];
    __syncthreads();
#pragma unroll
    for (int i = 0; i < 4; i++)
        Vt[(size_t)(d0 + ty + 8 * i) * S_LEN + s0 + tx] = tile[tx][ty + 8 * i];
}

// ---------------- pipelined bf16 MFMA GEMM, 64x128 tile, XCD N-striped ----------------
// R19: B always tile-packed (contiguous 1KB per staging wave-op); A packed when
// APACKED (QKV: hsb) else row-major gather (Wo: Ab). LDS image unchanged.
template <int APACKED, int OUTBF16>
__global__ __launch_bounds__(256) void gemm_pipe_kernel(const __hip_bfloat16* __restrict__ A,
                                                        const __hip_bfloat16* __restrict__ Bpk,
                                                        void* __restrict__ Cp,
                                                        int M, int N, int K, int stripe) {
    __shared__ __hip_bfloat16 As[4][2048];   // 4 x [64 rows][32 k]
    __shared__ __hip_bfloat16 Bs[4][4096];   // 4 x [128 rows][32 k]

    const int bid = blockIdx.x;
    const int x = bid & 7, j = bid >> 3;
    const int bn = (x * stripe + j % stripe) * 128;
    const int bm = (j / stripe) * 64;

    const int t = threadIdx.x, w = t >> 6, l = t & 63;
    const int wr = (w >> 1) * 32, wc = (w & 1) * 64;
    const int lr = l & 15;
    const int rdslot = (((l >> 4) ^ ((lr >> 1) & 3))) * 8;
    const int srow = w * 16 + (l >> 2);
    const int scol = (((l & 3) ^ ((l >> 3) & 3))) * 8;
    const int ldsoff = w * 512;

    // A source: packed tile stream or row-major gather
    const __hip_bfloat16* ga0 = APACKED
        ? A + (size_t)(bm >> 6) * 131072 + t * 8
        : A + (size_t)(bm + srow) * K + scol;
    // B source: packed tile stream
    const __hip_bfloat16* gb0 = Bpk + (size_t)(bn >> 7) * 262144 + t * 8;

    fx4 acc[2][4];
#pragma unroll
    for (int m = 0; m < 2; m++)
#pragma unroll
        for (int n = 0; n < 4; n++) acc[m][n] = (fx4){0.f, 0.f, 0.f, 0.f};

    const int T = K >> 5;

#define STAGE(kt, b)                                                      \
    do {                                                                  \
        const __hip_bfloat16* ga = APACKED ? ga0 + (kt) * 2048            \
                                           : ga0 + (kt) * 32;             \
        const __hip_bfloat16* gb = gb0 + (kt) * 4096;                     \
        GL_LDS16(ga,        &As[(b)][ldsoff]);                            \
        GL_LDS16(gb,        &Bs[(b)][ldsoff]);                            \
        GL_LDS16(gb + 2048, &Bs[(b)][2048 + ldsoff]);                     \
    } while (0)

    STAGE(0, 0);
    STAGE(1, 1);
    STAGE(2, 2);

    for (int i = 0; i < T; i++) {
        const int r = i & 3;
        if (i + 2 < T)      asm volatile("s_waitcnt vmcnt(6)" ::: "memory");
        else if (i + 1 < T) asm volatile("s_waitcnt vmcnt(3)" ::: "memory");
        else                asm volatile("s_waitcnt vmcnt(0)" ::: "memory");
        __builtin_amdgcn_s_barrier();
        asm volatile("" ::: "memory");
        if (i + 3 < T) STAGE(i + 3, (i + 3) & 3);

        bx8 af[2], bf[4];
#pragma unroll
        for (int m = 0; m < 2; m++)
            af[m] = *reinterpret_cast<const bx8*>(&As[r][(wr + m * 16 + lr) * 32 + rdslot]);
#pragma unroll
        for (int n = 0; n < 4; n++)
            bf[n] = *reinterpret_cast<const bx8*>(&Bs[r][(wc + n * 16 + lr) * 32 + rdslot]);
#pragma unroll
        for (int m = 0; m < 2; m++)
#pragma unroll
            for (int n = 0; n < 4; n++)
                acc[m][n] = __builtin_amdgcn_mfma_f32_16x16x32_bf16(af[m], bf[n], acc[m][n], 0, 0, 0);
    }
#undef STAGE

    const int lq = (l >> 4) * 4;
#pragma unroll
    for (int m = 0; m < 2; m++)
#pragma unroll
        for (int n = 0; n < 4; n++)
#pragma unroll
            for (int r2 = 0; r2 < 4; r2++) {
                int row = bm + wr + m * 16 + lq + r2;
                int col = bn + wc + n * 16 + lr;
                float v = acc[m][n][r2];
                if (OUTBF16)
                    ((__hip_bfloat16*)Cp)[(size_t)row * N + col] = __float2bfloat16(v);
                else
                    ((float*)Cp)[(size_t)row * N + col] = v;
            }
}

// ---------------- MFMA sliding-window flash attention, swapped-operand softmax (frozen R17) ----------------
__global__ __launch_bounds__(512, 4) void attn_kernel(const __hip_bfloat16* __restrict__ Q,
                                                      const __hip_bfloat16* __restrict__ Kg,
                                                      const __hip_bfloat16* __restrict__ Vtg,
                                                      __hip_bfloat16* __restrict__ Ab) {
    __shared__ __hip_bfloat16 Ks[2][4096];
    __shared__ __hip_bfloat16 Vs[2][4096];
    __shared__ __hip_bfloat16 Ps[QBLK * 64];

    const int bid = blockIdx.x;
    const int swz = (bid & 7) * 64 + (bid >> 3);
    const int h = swz >> 4, qi = swz & 15;
    const int qb = qi * QBLK;
    const int kvh = h >> 2;

    const int t = threadIdx.x, w = t >> 6, l = t & 63;
    const int lr = l & 15, g = l >> 4, lk = g * 8;
    const int qbw = qb + 16 * w;
    const int prow = 16 * w + lr;
    const int psz = (prow & 7) << 4;

    char* PsB = (char*)Ps;

    bx8 qa[2];
#pragma unroll
    for (int ks = 0; ks < 2; ks++)
        qa[ks] = *reinterpret_cast<const bx8*>(
            &Q[(size_t)(qbw + lr) * QKVN + h * HD + ks * 32 + lk]);

    fx4 ot[4];
#pragma unroll
    for (int n = 0; n < 4; n++) ot[n] = (fx4){0.f, 0.f, 0.f, 0.f};
    float mrow = -1e30f, srow = 0.f;

    const int k0_first = (qb >= 1024) ? (qb - 1024) : 0;
    const int k0_last  = qb + 64;
    const int wmax = qbw + 15;
    const int wlow = qbw - (WINDOW - 1);
    const int rowq = qbw + lr;

    const int sr = t >> 3, c8 = t & 7;
    const int scolsw = 8 * (c8 ^ (sr & 7));
    const int kcol = kvh * HD + scolsw;
    const int vrow = kvh * HD + sr;
    __hip_bfloat16* ldsK = &Ks[0][0] + (t >> 6) * 512;
    __hip_bfloat16* ldsV = &Vs[0][0] + (t >> 6) * 512;

#define ASTAGE(k0v, p)                                                           \
    do {                                                                         \
        GL_LDS16(&Kg[(size_t)((k0v) + sr) * QKVN + kcol], ldsK + (p) * 4096);    \
        GL_LDS16(&Vtg[(size_t)vrow * S_LEN + (k0v) + scolsw], ldsV + (p) * 4096);\
    } while (0)

    ASTAGE(k0_first, 0);

    int ti = 0;
    for (int k0 = k0_first; k0 <= k0_last; k0 += 64, ++ti) {
        const int p = ti & 1;
        asm volatile("s_waitcnt vmcnt(0)" ::: "memory");
        __builtin_amdgcn_s_barrier();
        asm volatile("" ::: "memory");
        if (k0 + 64 <= k0_last) ASTAGE(k0 + 64, p ^ 1);

        if (k0 <= wmax && k0 + 63 >= wlow) {
            char* KsB = (char*)&Ks[p][0];
            char* VsB = (char*)&Vs[p][0];
            bx8 kb[4][2];
#pragma unroll
            for (int n = 0; n < 4; n++)
#pragma unroll
                for (int ks = 0; ks < 2; ks++) {
                    int row = 16 * n + lr;
                    kb[n][ks] = *reinterpret_cast<const bx8*>(
                        KsB + row * 128 + (((ks * 64) + 16 * g) ^ ((row & 7) << 4)));
                }
            fx4 sc[4];
#pragma unroll
            for (int n = 0; n < 4; n++) {
                sc[n] = __builtin_amdgcn_mfma_f32_16x16x32_bf16(kb[n][0], qa[0],
                                                                (fx4){0.f, 0.f, 0.f, 0.f}, 0, 0, 0);
                sc[n] = __builtin_amdgcn_mfma_f32_16x16x32_bf16(kb[n][1], qa[1], sc[n], 0, 0, 0);
            }
            const bool interior = (k0 + 63 <= qbw) && (k0 >= qbw - 1008);
            if (interior) {
#pragma unroll
                for (int n = 0; n < 4; n++)
#pragma unroll
                    for (int r = 0; r < 4; r++) sc[n][r] *= 0.125f;
            } else {
#pragma unroll
                for (int n = 0; n < 4; n++)
#pragma unroll
                    for (int r = 0; r < 4; r++) {
                        int key = k0 + 16 * n + 4 * g + r;
                        bool valid = (key <= rowq) && (key >= rowq - (WINDOW - 1));
                        sc[n][r] = valid ? sc[n][r] * 0.125f : -1e30f;
                    }
            }
            float tmax = fmaxf(fmaxf(sc[0][0], sc[0][1]), fmaxf(sc[0][2], sc[0][3]));
#pragma unroll
            for (int n = 1; n < 4; n++)
                tmax = fmaxf(tmax, fmaxf(fmaxf(sc[n][0], sc[n][1]), fmaxf(sc[n][2], sc[n][3])));
            tmax = fmaxf(tmax, __shfl_xor(tmax, 16));
            tmax = fmaxf(tmax, __shfl_xor(tmax, 32));
            const bool grew = __any(tmax > mrow);
            float mn = mrow, fs = 1.f;
            if (grew) {
                mn = fmaxf(mrow, tmax);
                fs = __expf(mrow - mn);
                mrow = mn;
            }
            float ps = 0.f;
#pragma unroll
            for (int n = 0; n < 4; n++) {
#pragma unroll
                for (int r = 0; r < 4; r++) {
                    float p2 = __expf(sc[n][r] - mn);
                    sc[n][r] = p2;
                    ps += p2;
                }
                __hip_bfloat16 pk[4] __attribute__((aligned(8)));
                pk[0] = __float2bfloat16(sc[n][0]); pk[1] = __float2bfloat16(sc[n][1]);
                pk[2] = __float2bfloat16(sc[n][2]); pk[3] = __float2bfloat16(sc[n][3]);
                *reinterpret_cast<unsigned long long*>(PsB + prow * 128 + ((32 * n + 8 * g) ^ psz)) =
                    *reinterpret_cast<unsigned long long*>(pk);
            }
            ps += __shfl_xor(ps, 16);
            ps += __shfl_xor(ps, 32);
            if (grew) {
                srow = srow * fs + ps;
#pragma unroll
                for (int n = 0; n < 4; n++)
#pragma unroll
                    for (int r = 0; r < 4; r++) ot[n][r] *= fs;
            } else {
                srow += ps;
            }
            bx8 vb[4][2];
#pragma unroll
            for (int n = 0; n < 4; n++)
#pragma unroll
                for (int ks = 0; ks < 2; ks++) {
                    int row = 16 * n + lr;
                    vb[n][ks] = *reinterpret_cast<const bx8*>(
                        VsB + row * 128 + (((ks * 64) + 16 * g) ^ ((row & 7) << 4)));
                }
            bx8 pb[2];
#pragma unroll
            for (int ks = 0; ks < 2; ks++)
                pb[ks] = *reinterpret_cast<const bx8*>(
                    PsB + prow * 128 + (((ks * 64) + 16 * g) ^ psz));
#pragma unroll
            for (int n = 0; n < 4; n++) {
                ot[n] = __builtin_amdgcn_mfma_f32_16x16x32_bf16(vb[n][0], pb[0], ot[n], 0, 0, 0);
                ot[n] = __builtin_amdgcn_mfma_f32_16x16x32_bf16(vb[n][1], pb[1], ot[n], 0, 0, 0);
            }
        }
    }
#undef ASTAGE

    const float inv = 1.f / srow;
#pragma unroll
    for (int n = 0; n < 4; n++) {
        __hip_bfloat16 pk[4] __attribute__((aligned(8)));
#pragma unroll
        for (int r = 0; r < 4; r++) pk[r] = __float2bfloat16(ot[n][r] * inv);
        *reinterpret_cast<unsigned long long*>(PsB + prow * 128 + ((32 * n + 8 * g) ^ psz)) =
            *reinterpret_cast<unsigned long long*>(pk);
    }
    __syncthreads();
#pragma unroll
    for (int j = 0; j < 2; j++) {
        const int row = (t >> 3) + 64 * j, c = t & 7;   // 128 rows x 8 us8-chunks
        us8 v = *reinterpret_cast<const us8*>(PsB + row * 128 + ((c * 16) ^ ((row & 7) << 4)));
        *reinterpret_cast<us8*>(&Ab[(size_t)(qb + row) * HID + h * HD + c * 8]) = v;
    }
}

extern "C" void kernel_launch(void* const* d_in, const int* in_sizes, int n_in,
                              void* d_out, int out_size, void* d_ws, size_t ws_size,
                              hipStream_t stream) {
    const float* hs = (const float*)d_in[0];
    const float* Wq = (const float*)d_in[1];
    const float* Wk = (const float*)d_in[2];
    const float* Wv = (const float*)d_in[3];
    const float* Wo = (const float*)d_in[4];

    float* ws   = (float*)d_ws;
    float* cosT = ws;                  // 65536 f32
    float* sinT = cosT + 65536;        // 65536 f32
    __hip_bfloat16* hsb    = (__hip_bfloat16*)(sinT + 65536);   // [2048][2048] (tile-packed)
    __hip_bfloat16* WqkvT  = hsb + 4194304;                     // [3072][2048] (tile-packed)
    __hip_bfloat16* WoT    = WqkvT + 6291456;                   // [2048][2048] (tile-packed)
    __hip_bfloat16* QKVb   = WoT + 4194304;                     // [2048][3072] row-major
    __hip_bfloat16* Vt     = QKVb + 6291456;                    // [512][2048]
    __hip_bfloat16* Ab     = hsb;                               // alias: hsb dead after QKV gemm

    // prep: tables + hs->bf16(packed) + weight transposes(packed) (one dispatch)
    prep_kernel<<<12544, 256, 0, stream>>>(hs, Wq, Wk, Wv, Wo, cosT, sinT, hsb, WqkvT, WoT);

    // fused QKV projection (A packed, B packed; 768 blocks, XCD stripe=3)
    gemm_pipe_kernel<1, 1><<<768, 256, 0, stream>>>(hsb, WqkvT, QKVb, 2048, QKVN, 2048, 3);

    // RoPE (Q+K) + V transpose (one dispatch)
    ropev_kernel<<<11264, 256, 0, stream>>>(QKVb, Vt, cosT, sinT);

    // attention: 128-row blocks, 8 waves x 16 rows, writes row-major Ab directly
    attn_kernel<<<512, 512, 0, stream>>>(QKVb, QKVb + 2048, Vt, Ab);

    // output projection (A row-major gather, B packed; 512 blocks, XCD stripe=2)
    gemm_pipe_kernel<0, 0><<<512, 256, 0, stream>>>(Ab, WoT, d_out, 2048, 2048, 2048, 2);
}

// Round 20
// 144.030 us; speedup vs baseline: 1.0043x; 1.0043x over previous
//
#include <hip/hip_runtime.h>
#include <hip/hip_bf16.h>
#include <math.h>

#define S_LEN 2048
#define HID 2048
#define NH 32
#define NKV 8
#define HD 64
#define WINDOW 1024
#define QBLK 128
#define QKVN 3072   // fused Q(2048) | K(512) | V(512) columns

typedef __attribute__((ext_vector_type(8))) short bx8;          // 8 bf16 (4 VGPRs) — MFMA A/B frag
typedef __attribute__((ext_vector_type(4))) float fx4;          // MFMA C/D frag
typedef __attribute__((ext_vector_type(8))) unsigned short us8; // 8 bf16 raw

#define GL_LDS16(gp, lp) \
    __builtin_amdgcn_global_load_lds((__attribute__((address_space(1))) const void*)(gp), \
                                     (__attribute__((address_space(3))) void*)(lp), 16, 0, 0)

// Packed layouts (swizzle baked in; LDS image identical to previous rounds):
//   A (hsb):  tile (mt,kt) = 64rows x 32k, elem off = (mt*64+kt)*2048 + r*32 + s*8 + ko,
//             content chunk at slot s is s ^ ((r>>1)&3)
//   B (WqkvT/WoT): tile (nt,kt) = 128rows x 32k, elem off = (nt*64+kt)*4096 + r*32 + s*8 + ko

// ---------------- prep: rope tables + hs conv(packed, tile-per-block) + weight transposes(packed) ----------------
__global__ __launch_bounds__(256) void prep_kernel(const float* __restrict__ hs,
                                                   const float* __restrict__ Wq,
                                                   const float* __restrict__ Wk,
                                                   const float* __restrict__ Wv,
                                                   const float* __restrict__ Wo,
                                                   float* __restrict__ cosT, float* __restrict__ sinT,
                                                   __hip_bfloat16* __restrict__ hsb,
                                                   __hip_bfloat16* __restrict__ WqkvT,
                                                   __hip_bfloat16* __restrict__ WoT) {
    __shared__ float tile[32][33];
    int b = blockIdx.x, t = threadIdx.x;
    if (b < 256) {
        int idx = b * 256 + t;           // s*32 + f
        int s = idx >> 5, f = idx & 31;
        double inv = exp(-2.0 * (double)f / 64.0 * log(500000.0));
        double ang = (double)s * inv;
        cosT[idx] = (float)cos(ang);
        sinT[idx] = (float)sin(ang);
        return;
    }
    b -= 256;
    if (b < 2048) {
        // R20: one packed A-tile per block. b = mt*64+kt; thread t: row r=t>>2,
        // dst slot sl=t&3, src chunk = sl^((r>>1)&3). Wave writes 1KB contiguous.
        const int r = t >> 2, sl = t & 3;
        const int mt = b >> 6, kt = b & 63;
        const int chunk = sl ^ ((r >> 1) & 3);
        const float* src = &hs[(size_t)(mt * 64 + r) * 2048 + kt * 32 + chunk * 8];
        float4 a = *reinterpret_cast<const float4*>(src);
        float4 c = *reinterpret_cast<const float4*>(src + 4);
        __hip_bfloat16 o[8] __attribute__((aligned(16)));
        o[0] = __float2bfloat16(a.x); o[1] = __float2bfloat16(a.y);
        o[2] = __float2bfloat16(a.z); o[3] = __float2bfloat16(a.w);
        o[4] = __float2bfloat16(c.x); o[5] = __float2bfloat16(c.y);
        o[6] = __float2bfloat16(c.z); o[7] = __float2bfloat16(c.w);
        *reinterpret_cast<bx8*>(&hsb[(size_t)b * 2048 + t * 8]) = *reinterpret_cast<bx8*>(o);
        return;
    }
    b -= 2048;
    const float* src; __hip_bfloat16* dst; int Nd, bx, by, gbase;
    if (b < 4096)      { src = Wq; dst = WqkvT; Nd = 2048; bx = b & 63; by = b >> 6; gbase = 0; }
    else if (b < 5120) { b -= 4096; src = Wk; dst = WqkvT; Nd = 512; bx = b & 15; by = b >> 4; gbase = 2048; }
    else if (b < 6144) { b -= 5120; src = Wv; dst = WqkvT; Nd = 512; bx = b & 15; by = b >> 4; gbase = 2560; }
    else               { b -= 6144; src = Wo; dst = WoT;   Nd = 2048; bx = b & 63; by = b >> 6; gbase = 0; }
    int n0 = bx * 32, k0 = by * 32, tx = t & 31, ty = t >> 5;  // 32 x 8
#pragma unroll
    for (int i = 0; i < 4; i++)
        tile[ty + 8 * i][tx] = src[(size_t)(k0 + ty + 8 * i) * Nd + n0 + tx];
    __syncthreads();
    const int kt = k0 >> 5, chunk = tx >> 3, ko = tx & 7;
#pragma unroll
    for (int i = 0; i < 4; i++) {
        int gn = gbase + n0 + ty + 8 * i;
        int nt = gn >> 7, r = gn & 127;
        int s2 = chunk ^ ((r >> 1) & 3);
        dst[(size_t)(nt * 64 + kt) * 4096 + r * 32 + s2 * 8 + ko] =
            __float2bfloat16(tile[tx][ty + 8 * i]);
    }
}

// ---------------- rope (Q+K) + vtrans, ONE dispatch (frozen) ----------------
__global__ __launch_bounds__(256) void ropev_kernel(__hip_bfloat16* __restrict__ QKV,
                                                    __hip_bfloat16* __restrict__ Vt,
                                                    const float* __restrict__ cosT,
                                                    const float* __restrict__ sinT) {
    __shared__ __hip_bfloat16 tile[32][33];
    int b = blockIdx.x, t = threadIdx.x;
    if (b < 10240) {
        int idx = b * 256 + t;           // s*(40*32) + head*32 + f
        int f = idx & 31;
        int head = (idx >> 5) % (NH + NKV);
        int s = idx / ((NH + NKV) * 32);
        float c  = cosT[(s << 5) + f];
        float sn = sinT[(s << 5) + f];
        __hip_bfloat16* p = (head < NH) ? (QKV + (size_t)s * QKVN + head * HD)
                                        : (QKV + (size_t)s * QKVN + 2048 + (head - NH) * HD);
        float x1 = __bfloat162float(p[f]), x2 = __bfloat162float(p[f + 32]);
        p[f]      = __float2bfloat16(x1 * c - x2 * sn);
        p[f + 32] = __float2bfloat16(x2 * c + x1 * sn);
        return;
    }
    b -= 10240;
    int s0 = (b & 63) * 32, d0 = (b >> 6) * 32;
    int tx = t & 31, ty = t >> 5;  // 32 x 8
#pragma unroll
    for (int i = 0; i < 4; i++)
        tile[ty + 8 * i][tx] = QKV[(size_t)(s0 + ty + 8 * i) * QKVN + 2560 + d0 + tx];
    __syncthreads();
#pragma unroll
    for (int i = 0; i < 4; i++)
        Vt[(size_t)(d0 + ty + 8 * i) * S_LEN + s0 + tx] = tile[tx][ty + 8 * i];
}

// ---------------- pipelined bf16 MFMA GEMM, 64x128 tile, XCD N-striped (frozen R19) ----------------
template <int APACKED, int OUTBF16>
__global__ __launch_bounds__(256) void gemm_pipe_kernel(const __hip_bfloat16* __restrict__ A,
                                                        const __hip_bfloat16* __restrict__ Bpk,
                                                        void* __restrict__ Cp,
                                                        int M, int N, int K, int stripe) {
    __shared__ __hip_bfloat16 As[4][2048];   // 4 x [64 rows][32 k]
    __shared__ __hip_bfloat16 Bs[4][4096];   // 4 x [128 rows][32 k]

    const int bid = blockIdx.x;
    const int x = bid & 7, j = bid >> 3;
    const int bn = (x * stripe + j % stripe) * 128;
    const int bm = (j / stripe) * 64;

    const int t = threadIdx.x, w = t >> 6, l = t & 63;
    const int wr = (w >> 1) * 32, wc = (w & 1) * 64;
    const int lr = l & 15;
    const int rdslot = (((l >> 4) ^ ((lr >> 1) & 3))) * 8;
    const int srow = w * 16 + (l >> 2);
    const int scol = (((l & 3) ^ ((l >> 3) & 3))) * 8;
    const int ldsoff = w * 512;

    const __hip_bfloat16* ga0 = APACKED
        ? A + (size_t)(bm >> 6) * 131072 + t * 8
        : A + (size_t)(bm + srow) * K + scol;
    const __hip_bfloat16* gb0 = Bpk + (size_t)(bn >> 7) * 262144 + t * 8;

    fx4 acc[2][4];
#pragma unroll
    for (int m = 0; m < 2; m++)
#pragma unroll
        for (int n = 0; n < 4; n++) acc[m][n] = (fx4){0.f, 0.f, 0.f, 0.f};

    const int T = K >> 5;

#define STAGE(kt, b)                                                      \
    do {                                                                  \
        const __hip_bfloat16* ga = APACKED ? ga0 + (kt) * 2048            \
                                           : ga0 + (kt) * 32;             \
        const __hip_bfloat16* gb = gb0 + (kt) * 4096;                     \
        GL_LDS16(ga,        &As[(b)][ldsoff]);                            \
        GL_LDS16(gb,        &Bs[(b)][ldsoff]);                            \
        GL_LDS16(gb + 2048, &Bs[(b)][2048 + ldsoff]);                     \
    } while (0)

    STAGE(0, 0);
    STAGE(1, 1);
    STAGE(2, 2);

    for (int i = 0; i < T; i++) {
        const int r = i & 3;
        if (i + 2 < T)      asm volatile("s_waitcnt vmcnt(6)" ::: "memory");
        else if (i + 1 < T) asm volatile("s_waitcnt vmcnt(3)" ::: "memory");
        else                asm volatile("s_waitcnt vmcnt(0)" ::: "memory");
        __builtin_amdgcn_s_barrier();
        asm volatile("" ::: "memory");
        if (i + 3 < T) STAGE(i + 3, (i + 3) & 3);

        bx8 af[2], bf[4];
#pragma unroll
        for (int m = 0; m < 2; m++)
            af[m] = *reinterpret_cast<const bx8*>(&As[r][(wr + m * 16 + lr) * 32 + rdslot]);
#pragma unroll
        for (int n = 0; n < 4; n++)
            bf[n] = *reinterpret_cast<const bx8*>(&Bs[r][(wc + n * 16 + lr) * 32 + rdslot]);
#pragma unroll
        for (int m = 0; m < 2; m++)
#pragma unroll
            for (int n = 0; n < 4; n++)
                acc[m][n] = __builtin_amdgcn_mfma_f32_16x16x32_bf16(af[m], bf[n], acc[m][n], 0, 0, 0);
    }
#undef STAGE

    const int lq = (l >> 4) * 4;
#pragma unroll
    for (int m = 0; m < 2; m++)
#pragma unroll
        for (int n = 0; n < 4; n++)
#pragma unroll
            for (int r2 = 0; r2 < 4; r2++) {
                int row = bm + wr + m * 16 + lq + r2;
                int col = bn + wc + n * 16 + lr;
                float v = acc[m][n][r2];
                if (OUTBF16)
                    ((__hip_bfloat16*)Cp)[(size_t)row * N + col] = __float2bfloat16(v);
                else
                    ((float*)Cp)[(size_t)row * N + col] = v;
            }
}

// ---------------- MFMA sliding-window flash attention, swapped-operand softmax (frozen R17) ----------------
__global__ __launch_bounds__(512, 4) void attn_kernel(const __hip_bfloat16* __restrict__ Q,
                                                      const __hip_bfloat16* __restrict__ Kg,
                                                      const __hip_bfloat16* __restrict__ Vtg,
                                                      __hip_bfloat16* __restrict__ Ab) {
    __shared__ __hip_bfloat16 Ks[2][4096];
    __shared__ __hip_bfloat16 Vs[2][4096];
    __shared__ __hip_bfloat16 Ps[QBLK * 64];

    const int bid = blockIdx.x;
    const int swz = (bid & 7) * 64 + (bid >> 3);
    const int h = swz >> 4, qi = swz & 15;
    const int qb = qi * QBLK;
    const int kvh = h >> 2;

    const int t = threadIdx.x, w = t >> 6, l = t & 63;
    const int lr = l & 15, g = l >> 4, lk = g * 8;
    const int qbw = qb + 16 * w;
    const int prow = 16 * w + lr;
    const int psz = (prow & 7) << 4;

    char* PsB = (char*)Ps;

    bx8 qa[2];
#pragma unroll
    for (int ks = 0; ks < 2; ks++)
        qa[ks] = *reinterpret_cast<const bx8*>(
            &Q[(size_t)(qbw + lr) * QKVN + h * HD + ks * 32 + lk]);

    fx4 ot[4];
#pragma unroll
    for (int n = 0; n < 4; n++) ot[n] = (fx4){0.f, 0.f, 0.f, 0.f};
    float mrow = -1e30f, srow = 0.f;

    const int k0_first = (qb >= 1024) ? (qb - 1024) : 0;
    const int k0_last  = qb + 64;
    const int wmax = qbw + 15;
    const int wlow = qbw - (WINDOW - 1);
    const int rowq = qbw + lr;

    const int sr = t >> 3, c8 = t & 7;
    const int scolsw = 8 * (c8 ^ (sr & 7));
    const int kcol = kvh * HD + scolsw;
    const int vrow = kvh * HD + sr;
    __hip_bfloat16* ldsK = &Ks[0][0] + (t >> 6) * 512;
    __hip_bfloat16* ldsV = &Vs[0][0] + (t >> 6) * 512;

#define ASTAGE(k0v, p)                                                           \
    do {                                                                         \
        GL_LDS16(&Kg[(size_t)((k0v) + sr) * QKVN + kcol], ldsK + (p) * 4096);    \
        GL_LDS16(&Vtg[(size_t)vrow * S_LEN + (k0v) + scolsw], ldsV + (p) * 4096);\
    } while (0)

    ASTAGE(k0_first, 0);

    int ti = 0;
    for (int k0 = k0_first; k0 <= k0_last; k0 += 64, ++ti) {
        const int p = ti & 1;
        asm volatile("s_waitcnt vmcnt(0)" ::: "memory");
        __builtin_amdgcn_s_barrier();
        asm volatile("" ::: "memory");
        if (k0 + 64 <= k0_last) ASTAGE(k0 + 64, p ^ 1);

        if (k0 <= wmax && k0 + 63 >= wlow) {
            char* KsB = (char*)&Ks[p][0];
            char* VsB = (char*)&Vs[p][0];
            bx8 kb[4][2];
#pragma unroll
            for (int n = 0; n < 4; n++)
#pragma unroll
                for (int ks = 0; ks < 2; ks++) {
                    int row = 16 * n + lr;
                    kb[n][ks] = *reinterpret_cast<const bx8*>(
                        KsB + row * 128 + (((ks * 64) + 16 * g) ^ ((row & 7) << 4)));
                }
            fx4 sc[4];
#pragma unroll
            for (int n = 0; n < 4; n++) {
                sc[n] = __builtin_amdgcn_mfma_f32_16x16x32_bf16(kb[n][0], qa[0],
                                                                (fx4){0.f, 0.f, 0.f, 0.f}, 0, 0, 0);
                sc[n] = __builtin_amdgcn_mfma_f32_16x16x32_bf16(kb[n][1], qa[1], sc[n], 0, 0, 0);
            }
            const bool interior = (k0 + 63 <= qbw) && (k0 >= qbw - 1008);
            if (interior) {
#pragma unroll
                for (int n = 0; n < 4; n++)
#pragma unroll
                    for (int r = 0; r < 4; r++) sc[n][r] *= 0.125f;
            } else {
#pragma unroll
                for (int n = 0; n < 4; n++)
#pragma unroll
                    for (int r = 0; r < 4; r++) {
                        int key = k0 + 16 * n + 4 * g + r;
                        bool valid = (key <= rowq) && (key >= rowq - (WINDOW - 1));
                        sc[n][r] = valid ? sc[n][r] * 0.125f : -1e30f;
                    }
            }
            float tmax = fmaxf(fmaxf(sc[0][0], sc[0][1]), fmaxf(sc[0][2], sc[0][3]));
#pragma unroll
            for (int n = 1; n < 4; n++)
                tmax = fmaxf(tmax, fmaxf(fmaxf(sc[n][0], sc[n][1]), fmaxf(sc[n][2], sc[n][3])));
            tmax = fmaxf(tmax, __shfl_xor(tmax, 16));
            tmax = fmaxf(tmax, __shfl_xor(tmax, 32));
            const bool grew = __any(tmax > mrow);
            float mn = mrow, fs = 1.f;
            if (grew) {
                mn = fmaxf(mrow, tmax);
                fs = __expf(mrow - mn);
                mrow = mn;
            }
            float ps = 0.f;
#pragma unroll
            for (int n = 0; n < 4; n++) {
#pragma unroll
                for (int r = 0; r < 4; r++) {
                    float p2 = __expf(sc[n][r] - mn);
                    sc[n][r] = p2;
                    ps += p2;
                }
                __hip_bfloat16 pk[4] __attribute__((aligned(8)));
                pk[0] = __float2bfloat16(sc[n][0]); pk[1] = __float2bfloat16(sc[n][1]);
                pk[2] = __float2bfloat16(sc[n][2]); pk[3] = __float2bfloat16(sc[n][3]);
                *reinterpret_cast<unsigned long long*>(PsB + prow * 128 + ((32 * n + 8 * g) ^ psz)) =
                    *reinterpret_cast<unsigned long long*>(pk);
            }
            ps += __shfl_xor(ps, 16);
            ps += __shfl_xor(ps, 32);
            if (grew) {
                srow = srow * fs + ps;
#pragma unroll
                for (int n = 0; n < 4; n++)
#pragma unroll
                    for (int r = 0; r < 4; r++) ot[n][r] *= fs;
            } else {
                srow += ps;
            }
            bx8 vb[4][2];
#pragma unroll
            for (int n = 0; n < 4; n++)
#pragma unroll
                for (int ks = 0; ks < 2; ks++) {
                    int row = 16 * n + lr;
                    vb[n][ks] = *reinterpret_cast<const bx8*>(
                        VsB + row * 128 + (((ks * 64) + 16 * g) ^ ((row & 7) << 4)));
                }
            bx8 pb[2];
#pragma unroll
            for (int ks = 0; ks < 2; ks++)
                pb[ks] = *reinterpret_cast<const bx8*>(
                    PsB + prow * 128 + (((ks * 64) + 16 * g) ^ psz));
#pragma unroll
            for (int n = 0; n < 4; n++) {
                ot[n] = __builtin_amdgcn_mfma_f32_16x16x32_bf16(vb[n][0], pb[0], ot[n], 0, 0, 0);
                ot[n] = __builtin_amdgcn_mfma_f32_16x16x32_bf16(vb[n][1], pb[1], ot[n], 0, 0, 0);
            }
        }
    }
#undef ASTAGE

    const float inv = 1.f / srow;
#pragma unroll
    for (int n = 0; n < 4; n++) {
        __hip_bfloat16 pk[4] __attribute__((aligned(8)));
#pragma unroll
        for (int r = 0; r < 4; r++) pk[r] = __float2bfloat16(ot[n][r] * inv);
        *reinterpret_cast<unsigned long long*>(PsB + prow * 128 + ((32 * n + 8 * g) ^ psz)) =
            *reinterpret_cast<unsigned long long*>(pk);
    }
    __syncthreads();
#pragma unroll
    for (int j = 0; j < 2; j++) {
        const int row = (t >> 3) + 64 * j, c = t & 7;   // 128 rows x 8 us8-chunks
        us8 v = *reinterpret_cast<const us8*>(PsB + row * 128 + ((c * 16) ^ ((row & 7) << 4)));
        *reinterpret_cast<us8*>(&Ab[(size_t)(qb + row) * HID + h * HD + c * 8]) = v;
    }
}

extern "C" void kernel_launch(void* const* d_in, const int* in_sizes, int n_in,
                              void* d_out, int out_size, void* d_ws, size_t ws_size,
                              hipStream_t stream) {
    const float* hs = (const float*)d_in[0];
    const float* Wq = (const float*)d_in[1];
    const float* Wk = (const float*)d_in[2];
    const float* Wv = (const float*)d_in[3];
    const float* Wo = (const float*)d_in[4];

    float* ws   = (float*)d_ws;
    float* cosT = ws;                  // 65536 f32
    float* sinT = cosT + 65536;        // 65536 f32
    __hip_bfloat16* hsb    = (__hip_bfloat16*)(sinT + 65536);   // [2048][2048] (tile-packed)
    __hip_bfloat16* WqkvT  = hsb + 4194304;                     // [3072][2048] (tile-packed)
    __hip_bfloat16* WoT    = WqkvT + 6291456;                   // [2048][2048] (tile-packed)
    __hip_bfloat16* QKVb   = WoT + 4194304;                     // [2048][3072] row-major
    __hip_bfloat16* Vt     = QKVb + 6291456;                    // [512][2048]
    __hip_bfloat16* Ab     = hsb;                               // alias: hsb dead after QKV gemm

    // prep: tables + hs->bf16(packed, coalesced) + weight transposes(packed)
    prep_kernel<<<12544, 256, 0, stream>>>(hs, Wq, Wk, Wv, Wo, cosT, sinT, hsb, WqkvT, WoT);

    // fused QKV projection (A packed, B packed; 768 blocks, XCD stripe=3)
    gemm_pipe_kernel<1, 1><<<768, 256, 0, stream>>>(hsb, WqkvT, QKVb, 2048, QKVN, 2048, 3);

    // RoPE (Q+K) + V transpose (one dispatch)
    ropev_kernel<<<11264, 256, 0, stream>>>(QKVb, Vt, cosT, sinT);

    // attention: 128-row blocks, 8 waves x 16 rows, writes row-major Ab directly
    attn_kernel<<<512, 512, 0, stream>>>(QKVb, QKVb + 2048, Vt, Ab);

    // output projection (A row-major gather, B packed; 512 blocks, XCD stripe=2)
    gemm_pipe_kernel<0, 0><<<512, 256, 0, stream>>>(Ab, WoT, d_out, 2048, 2048, 2048, 2);
}

// Round 21
// 140.533 us; speedup vs baseline: 1.0293x; 1.0249x over previous
//
#include <hip/hip_runtime.h>
#include <hip/hip_bf16.h>
#include <math.h>

#define S_LEN 2048
#define HID 2048
#define NH 32
#define NKV 8
#define HD 64
#define WINDOW 1024
#define QBLK 128
#define QKVN 3072   // fused Q(2048) | K(512) | V(512) columns

typedef __attribute__((ext_vector_type(8))) short bx8;          // 8 bf16 (4 VGPRs) — MFMA A/B frag
typedef __attribute__((ext_vector_type(4))) float fx4;          // MFMA C/D frag
typedef __attribute__((ext_vector_type(8))) unsigned short us8; // 8 bf16 raw

#define GL_LDS16(gp, lp) \
    __builtin_amdgcn_global_load_lds((__attribute__((address_space(1))) const void*)(gp), \
                                     (__attribute__((address_space(3))) void*)(lp), 16, 0, 0)

// Packed layouts (swizzle baked in; LDS image identical to previous rounds):
//   A: tile (mt,kt) = 64rows x 32k, elem off = (mt*64+kt)*2048 + r*32 + s*8 + ko,
//      content chunk at slot s is s ^ ((r>>1)&3)
//   B: tile (nt,kt) = 128rows x 32k, elem off = (nt*64+kt)*4096 + r*32 + s*8 + ko

// ---------------- prep: rope tables + hs conv(packed) + weight transposes(packed) ----------------
__global__ __launch_bounds__(256) void prep_kernel(const float* __restrict__ hs,
                                                   const float* __restrict__ Wq,
                                                   const float* __restrict__ Wk,
                                                   const float* __restrict__ Wv,
                                                   const float* __restrict__ Wo,
                                                   float* __restrict__ cosT, float* __restrict__ sinT,
                                                   __hip_bfloat16* __restrict__ hsb,
                                                   __hip_bfloat16* __restrict__ WqkvT,
                                                   __hip_bfloat16* __restrict__ WoT) {
    __shared__ float tile[32][33];
    int b = blockIdx.x, t = threadIdx.x;
    if (b < 256) {
        int idx = b * 256 + t;           // s*32 + f
        int s = idx >> 5, f = idx & 31;
        double inv = exp(-2.0 * (double)f / 64.0 * log(500000.0));
        double ang = (double)s * inv;
        cosT[idx] = (float)cos(ang);
        sinT[idx] = (float)sin(ang);
        return;
    }
    b -= 256;
    if (b < 2048) {
        // one packed A-tile per block. b = mt*64+kt; thread t: row r=t>>2,
        // dst slot sl=t&3, src chunk = sl^((r>>1)&3). Wave writes 1KB contiguous.
        const int r = t >> 2, sl = t & 3;
        const int mt = b >> 6, kt = b & 63;
        const int chunk = sl ^ ((r >> 1) & 3);
        const float* src = &hs[(size_t)(mt * 64 + r) * 2048 + kt * 32 + chunk * 8];
        float4 a = *reinterpret_cast<const float4*>(src);
        float4 c = *reinterpret_cast<const float4*>(src + 4);
        __hip_bfloat16 o[8] __attribute__((aligned(16)));
        o[0] = __float2bfloat16(a.x); o[1] = __float2bfloat16(a.y);
        o[2] = __float2bfloat16(a.z); o[3] = __float2bfloat16(a.w);
        o[4] = __float2bfloat16(c.x); o[5] = __float2bfloat16(c.y);
        o[6] = __float2bfloat16(c.z); o[7] = __float2bfloat16(c.w);
        *reinterpret_cast<bx8*>(&hsb[(size_t)b * 2048 + t * 8]) = *reinterpret_cast<bx8*>(o);
        return;
    }
    b -= 2048;
    const float* src; __hip_bfloat16* dst; int Nd, bx, by, gbase;
    if (b < 4096)      { src = Wq; dst = WqkvT; Nd = 2048; bx = b & 63; by = b >> 6; gbase = 0; }
    else if (b < 5120) { b -= 4096; src = Wk; dst = WqkvT; Nd = 512; bx = b & 15; by = b >> 4; gbase = 2048; }
    else if (b < 6144) { b -= 5120; src = Wv; dst = WqkvT; Nd = 512; bx = b & 15; by = b >> 4; gbase = 2560; }
    else               { b -= 6144; src = Wo; dst = WoT;   Nd = 2048; bx = b & 63; by = b >> 6; gbase = 0; }
    int n0 = bx * 32, k0 = by * 32, tx = t & 31, ty = t >> 5;  // 32 x 8
#pragma unroll
    for (int i = 0; i < 4; i++)
        tile[ty + 8 * i][tx] = src[(size_t)(k0 + ty + 8 * i) * Nd + n0 + tx];
    __syncthreads();
    const int kt = k0 >> 5, chunk = tx >> 3, ko = tx & 7;
#pragma unroll
    for (int i = 0; i < 4; i++) {
        int gn = gbase + n0 + ty + 8 * i;
        int nt = gn >> 7, r = gn & 127;
        int s2 = chunk ^ ((r >> 1) & 3);
        dst[(size_t)(nt * 64 + kt) * 4096 + r * 32 + s2 * 8 + ko] =
            __float2bfloat16(tile[tx][ty + 8 * i]);
    }
}

// ---------------- V transpose only (RoPE now fused into the QKV GEMM epilogue) ----------------
__global__ __launch_bounds__(256) void vtrans_kernel(const __hip_bfloat16* __restrict__ QKV,
                                                     __hip_bfloat16* __restrict__ Vt) {
    __shared__ __hip_bfloat16 tile[32][33];
    int b = blockIdx.x, t = threadIdx.x;
    int s0 = (b & 63) * 32, d0 = (b >> 6) * 32;
    int tx = t & 31, ty = t >> 5;  // 32 x 8
#pragma unroll
    for (int i = 0; i < 4; i++)
        tile[ty + 8 * i][tx] = QKV[(size_t)(s0 + ty + 8 * i) * QKVN + 2560 + d0 + tx];
    __syncthreads();
#pragma unroll
    for (int i = 0; i < 4; i++)
        Vt[(size_t)(d0 + ty + 8 * i) * S_LEN + s0 + tx] = tile[tx][ty + 8 * i];
}

// ---------------- pipelined bf16 MFMA GEMM, 64x128 tile, XCD N-striped ----------------
// R21: ROPE=1 applies RoPE in the epilogue to Q/K columns (wave col span = one
// head; rotate pair (f,f+32) lives in acc[m][n]/acc[m][n+2] of the same thread).
template <int APACKED, int OUTBF16, int ROPE>
__global__ __launch_bounds__(256) void gemm_pipe_kernel(const __hip_bfloat16* __restrict__ A,
                                                        const __hip_bfloat16* __restrict__ Bpk,
                                                        void* __restrict__ Cp,
                                                        const float* __restrict__ cosT,
                                                        const float* __restrict__ sinT,
                                                        int M, int N, int K, int stripe) {
    __shared__ __hip_bfloat16 As[4][2048];   // 4 x [64 rows][32 k]
    __shared__ __hip_bfloat16 Bs[4][4096];   // 4 x [128 rows][32 k]

    const int bid = blockIdx.x;
    const int x = bid & 7, j = bid >> 3;
    const int bn = (x * stripe + j % stripe) * 128;
    const int bm = (j / stripe) * 64;

    const int t = threadIdx.x, w = t >> 6, l = t & 63;
    const int wr = (w >> 1) * 32, wc = (w & 1) * 64;
    const int lr = l & 15;
    const int rdslot = (((l >> 4) ^ ((lr >> 1) & 3))) * 8;
    const int srow = w * 16 + (l >> 2);
    const int scol = (((l & 3) ^ ((l >> 3) & 3))) * 8;
    const int ldsoff = w * 512;

    const __hip_bfloat16* ga0 = APACKED
        ? A + (size_t)(bm >> 6) * 131072 + t * 8
        : A + (size_t)(bm + srow) * K + scol;
    const __hip_bfloat16* gb0 = Bpk + (size_t)(bn >> 7) * 262144 + t * 8;

    fx4 acc[2][4];
#pragma unroll
    for (int m = 0; m < 2; m++)
#pragma unroll
        for (int n = 0; n < 4; n++) acc[m][n] = (fx4){0.f, 0.f, 0.f, 0.f};

    const int T = K >> 5;

#define STAGE(kt, b)                                                      \
    do {                                                                  \
        const __hip_bfloat16* ga = APACKED ? ga0 + (kt) * 2048            \
                                           : ga0 + (kt) * 32;             \
        const __hip_bfloat16* gb = gb0 + (kt) * 4096;                     \
        GL_LDS16(ga,        &As[(b)][ldsoff]);                            \
        GL_LDS16(gb,        &Bs[(b)][ldsoff]);                            \
        GL_LDS16(gb + 2048, &Bs[(b)][2048 + ldsoff]);                     \
    } while (0)

    STAGE(0, 0);
    STAGE(1, 1);
    STAGE(2, 2);

    for (int i = 0; i < T; i++) {
        const int r = i & 3;
        if (i + 2 < T)      asm volatile("s_waitcnt vmcnt(6)" ::: "memory");
        else if (i + 1 < T) asm volatile("s_waitcnt vmcnt(3)" ::: "memory");
        else                asm volatile("s_waitcnt vmcnt(0)" ::: "memory");
        __builtin_amdgcn_s_barrier();
        asm volatile("" ::: "memory");
        if (i + 3 < T) STAGE(i + 3, (i + 3) & 3);

        bx8 af[2], bf[4];
#pragma unroll
        for (int m = 0; m < 2; m++)
            af[m] = *reinterpret_cast<const bx8*>(&As[r][(wr + m * 16 + lr) * 32 + rdslot]);
#pragma unroll
        for (int n = 0; n < 4; n++)
            bf[n] = *reinterpret_cast<const bx8*>(&Bs[r][(wc + n * 16 + lr) * 32 + rdslot]);
#pragma unroll
        for (int m = 0; m < 2; m++)
#pragma unroll
            for (int n = 0; n < 4; n++)
                acc[m][n] = __builtin_amdgcn_mfma_f32_16x16x32_bf16(af[m], bf[n], acc[m][n], 0, 0, 0);
    }
#undef STAGE

    const int lq = (l >> 4) * 4;
    const bool doRope = ROPE && (bn + wc) < 2560;   // Q or K head (V skips)
#pragma unroll
    for (int m = 0; m < 2; m++)
#pragma unroll
        for (int r2 = 0; r2 < 4; r2++) {
            const int row = bm + wr + m * 16 + lq + r2;
            float v0 = acc[m][0][r2], v1 = acc[m][1][r2];
            float v2 = acc[m][2][r2], v3 = acc[m][3][r2];
            if (doRope) {
                float c0 = cosT[(row << 5) + lr],      s0 = sinT[(row << 5) + lr];
                float c1 = cosT[(row << 5) + 16 + lr], s1 = sinT[(row << 5) + 16 + lr];
                float o0 = v0 * c0 - v2 * s0, o2 = v2 * c0 + v0 * s0;
                float o1 = v1 * c1 - v3 * s1, o3 = v3 * c1 + v1 * s1;
                v0 = o0; v1 = o1; v2 = o2; v3 = o3;
            }
            float vv[4] = {v0, v1, v2, v3};
#pragma unroll
            for (int n = 0; n < 4; n++) {
                int col = bn + wc + 16 * n + lr;
                if (OUTBF16)
                    ((__hip_bfloat16*)Cp)[(size_t)row * N + col] = __float2bfloat16(vv[n]);
                else
                    ((float*)Cp)[(size_t)row * N + col] = vv[n];
            }
        }
}

// ---------------- MFMA sliding-window flash attention, swapped-operand softmax ----------------
// R21: epilogue writes Ab in PACKED-A layout (slot = (c&3)^((rloc>>1)&3)) so the
// Wo GEMM can use the packed staging fast path. Core frozen from R17.
__global__ __launch_bounds__(512, 4) void attn_kernel(const __hip_bfloat16* __restrict__ Q,
                                                      const __hip_bfloat16* __restrict__ Kg,
                                                      const __hip_bfloat16* __restrict__ Vtg,
                                                      __hip_bfloat16* __restrict__ Ab) {
    __shared__ __hip_bfloat16 Ks[2][4096];
    __shared__ __hip_bfloat16 Vs[2][4096];
    __shared__ __hip_bfloat16 Ps[QBLK * 64];

    const int bid = blockIdx.x;
    const int swz = (bid & 7) * 64 + (bid >> 3);
    const int h = swz >> 4, qi = swz & 15;
    const int qb = qi * QBLK;
    const int kvh = h >> 2;

    const int t = threadIdx.x, w = t >> 6, l = t & 63;
    const int lr = l & 15, g = l >> 4, lk = g * 8;
    const int qbw = qb + 16 * w;
    const int prow = 16 * w + lr;
    const int psz = (prow & 7) << 4;

    char* PsB = (char*)Ps;

    bx8 qa[2];
#pragma unroll
    for (int ks = 0; ks < 2; ks++)
        qa[ks] = *reinterpret_cast<const bx8*>(
            &Q[(size_t)(qbw + lr) * QKVN + h * HD + ks * 32 + lk]);

    fx4 ot[4];
#pragma unroll
    for (int n = 0; n < 4; n++) ot[n] = (fx4){0.f, 0.f, 0.f, 0.f};
    float mrow = -1e30f, srow = 0.f;

    const int k0_first = (qb >= 1024) ? (qb - 1024) : 0;
    const int k0_last  = qb + 64;
    const int wmax = qbw + 15;
    const int wlow = qbw - (WINDOW - 1);
    const int rowq = qbw + lr;

    const int sr = t >> 3, c8 = t & 7;
    const int scolsw = 8 * (c8 ^ (sr & 7));
    const int kcol = kvh * HD + scolsw;
    const int vrow = kvh * HD + sr;
    __hip_bfloat16* ldsK = &Ks[0][0] + (t >> 6) * 512;
    __hip_bfloat16* ldsV = &Vs[0][0] + (t >> 6) * 512;

#define ASTAGE(k0v, p)                                                           \
    do {                                                                         \
        GL_LDS16(&Kg[(size_t)((k0v) + sr) * QKVN + kcol], ldsK + (p) * 4096);    \
        GL_LDS16(&Vtg[(size_t)vrow * S_LEN + (k0v) + scolsw], ldsV + (p) * 4096);\
    } while (0)

    ASTAGE(k0_first, 0);

    int ti = 0;
    for (int k0 = k0_first; k0 <= k0_last; k0 += 64, ++ti) {
        const int p = ti & 1;
        asm volatile("s_waitcnt vmcnt(0)" ::: "memory");
        __builtin_amdgcn_s_barrier();
        asm volatile("" ::: "memory");
        if (k0 + 64 <= k0_last) ASTAGE(k0 + 64, p ^ 1);

        if (k0 <= wmax && k0 + 63 >= wlow) {
            char* KsB = (char*)&Ks[p][0];
            char* VsB = (char*)&Vs[p][0];
            bx8 kb[4][2];
#pragma unroll
            for (int n = 0; n < 4; n++)
#pragma unroll
                for (int ks = 0; ks < 2; ks++) {
                    int row = 16 * n + lr;
                    kb[n][ks] = *reinterpret_cast<const bx8*>(
                        KsB + row * 128 + (((ks * 64) + 16 * g) ^ ((row & 7) << 4)));
                }
            fx4 sc[4];
#pragma unroll
            for (int n = 0; n < 4; n++) {
                sc[n] = __builtin_amdgcn_mfma_f32_16x16x32_bf16(kb[n][0], qa[0],
                                                                (fx4){0.f, 0.f, 0.f, 0.f}, 0, 0, 0);
                sc[n] = __builtin_amdgcn_mfma_f32_16x16x32_bf16(kb[n][1], qa[1], sc[n], 0, 0, 0);
            }
            const bool interior = (k0 + 63 <= qbw) && (k0 >= qbw - 1008);
            if (interior) {
#pragma unroll
                for (int n = 0; n < 4; n++)
#pragma unroll
                    for (int r = 0; r < 4; r++) sc[n][r] *= 0.125f;
            } else {
#pragma unroll
                for (int n = 0; n < 4; n++)
#pragma unroll
                    for (int r = 0; r < 4; r++) {
                        int key = k0 + 16 * n + 4 * g + r;
                        bool valid = (key <= rowq) && (key >= rowq - (WINDOW - 1));
                        sc[n][r] = valid ? sc[n][r] * 0.125f : -1e30f;
                    }
            }
            float tmax = fmaxf(fmaxf(sc[0][0], sc[0][1]), fmaxf(sc[0][2], sc[0][3]));
#pragma unroll
            for (int n = 1; n < 4; n++)
                tmax = fmaxf(tmax, fmaxf(fmaxf(sc[n][0], sc[n][1]), fmaxf(sc[n][2], sc[n][3])));
            tmax = fmaxf(tmax, __shfl_xor(tmax, 16));
            tmax = fmaxf(tmax, __shfl_xor(tmax, 32));
            const bool grew = __any(tmax > mrow);
            float mn = mrow, fs = 1.f;
            if (grew) {
                mn = fmaxf(mrow, tmax);
                fs = __expf(mrow - mn);
                mrow = mn;
            }
            float ps = 0.f;
#pragma unroll
            for (int n = 0; n < 4; n++) {
#pragma unroll
                for (int r = 0; r < 4; r++) {
                    float p2 = __expf(sc[n][r] - mn);
                    sc[n][r] = p2;
                    ps += p2;
                }
                __hip_bfloat16 pk[4] __attribute__((aligned(8)));
                pk[0] = __float2bfloat16(sc[n][0]); pk[1] = __float2bfloat16(sc[n][1]);
                pk[2] = __float2bfloat16(sc[n][2]); pk[3] = __float2bfloat16(sc[n][3]);
                *reinterpret_cast<unsigned long long*>(PsB + prow * 128 + ((32 * n + 8 * g) ^ psz)) =
                    *reinterpret_cast<unsigned long long*>(pk);
            }
            ps += __shfl_xor(ps, 16);
            ps += __shfl_xor(ps, 32);
            if (grew) {
                srow = srow * fs + ps;
#pragma unroll
                for (int n = 0; n < 4; n++)
#pragma unroll
                    for (int r = 0; r < 4; r++) ot[n][r] *= fs;
            } else {
                srow += ps;
            }
            bx8 vb[4][2];
#pragma unroll
            for (int n = 0; n < 4; n++)
#pragma unroll
                for (int ks = 0; ks < 2; ks++) {
                    int row = 16 * n + lr;
                    vb[n][ks] = *reinterpret_cast<const bx8*>(
                        VsB + row * 128 + (((ks * 64) + 16 * g) ^ ((row & 7) << 4)));
                }
            bx8 pb[2];
#pragma unroll
            for (int ks = 0; ks < 2; ks++)
                pb[ks] = *reinterpret_cast<const bx8*>(
                    PsB + prow * 128 + (((ks * 64) + 16 * g) ^ psz));
#pragma unroll
            for (int n = 0; n < 4; n++) {
                ot[n] = __builtin_amdgcn_mfma_f32_16x16x32_bf16(vb[n][0], pb[0], ot[n], 0, 0, 0);
                ot[n] = __builtin_amdgcn_mfma_f32_16x16x32_bf16(vb[n][1], pb[1], ot[n], 0, 0, 0);
            }
        }
    }
#undef ASTAGE

    // ---- epilogue: normalize, O^T frags -> Ps as [q][d], then PACKED-A write ----
    const float inv = 1.f / srow;
#pragma unroll
    for (int n = 0; n < 4; n++) {
        __hip_bfloat16 pk[4] __attribute__((aligned(8)));
#pragma unroll
        for (int r = 0; r < 4; r++) pk[r] = __float2bfloat16(ot[n][r] * inv);
        *reinterpret_cast<unsigned long long*>(PsB + prow * 128 + ((32 * n + 8 * g) ^ psz)) =
            *reinterpret_cast<unsigned long long*>(pk);
    }
    __syncthreads();
#pragma unroll
    for (int j = 0; j < 2; j++) {
        const int row = (t >> 3) + 64 * j, c = t & 7;   // 128 rows x 8 us8-chunks
        us8 v = *reinterpret_cast<const us8*>(PsB + row * 128 + ((c * 16) ^ ((row & 7) << 4)));
        const int R = qb + row;
        const int mt = R >> 6, rloc = R & 63;
        const int kt = 2 * h + (c >> 2);
        const int slot = (c & 3) ^ ((rloc >> 1) & 3);
        *reinterpret_cast<us8*>(&Ab[(size_t)(mt * 64 + kt) * 2048 + rloc * 32 + slot * 8]) = v;
    }
}

extern "C" void kernel_launch(void* const* d_in, const int* in_sizes, int n_in,
                              void* d_out, int out_size, void* d_ws, size_t ws_size,
                              hipStream_t stream) {
    const float* hs = (const float*)d_in[0];
    const float* Wq = (const float*)d_in[1];
    const float* Wk = (const float*)d_in[2];
    const float* Wv = (const float*)d_in[3];
    const float* Wo = (const float*)d_in[4];

    float* ws   = (float*)d_ws;
    float* cosT = ws;                  // 65536 f32
    float* sinT = cosT + 65536;        // 65536 f32
    __hip_bfloat16* hsb    = (__hip_bfloat16*)(sinT + 65536);   // [2048][2048] (packed A)
    __hip_bfloat16* WqkvT  = hsb + 4194304;                     // [3072][2048] (packed B)
    __hip_bfloat16* WoT    = WqkvT + 6291456;                   // [2048][2048] (packed B)
    __hip_bfloat16* QKVb   = WoT + 4194304;                     // [2048][3072] row-major
    __hip_bfloat16* Vt     = QKVb + 6291456;                    // [512][2048]
    __hip_bfloat16* Ab     = hsb;                               // alias: packed A for Wo gemm

    // prep: tables + hs->bf16(packed) + weight transposes(packed)
    prep_kernel<<<12544, 256, 0, stream>>>(hs, Wq, Wk, Wv, Wo, cosT, sinT, hsb, WqkvT, WoT);

    // fused QKV projection + RoPE-in-epilogue (A packed, B packed)
    gemm_pipe_kernel<1, 1, 1><<<768, 256, 0, stream>>>(hsb, WqkvT, QKVb, cosT, sinT,
                                                       2048, QKVN, 2048, 3);

    // V transpose only (RoPE done in GEMM)
    vtrans_kernel<<<1024, 256, 0, stream>>>(QKVb, Vt);

    // attention: writes Ab in packed-A layout
    attn_kernel<<<512, 512, 0, stream>>>(QKVb, QKVb + 2048, Vt, Ab);

    // output projection (A packed now, B packed)
    gemm_pipe_kernel<1, 0, 0><<<512, 256, 0, stream>>>(Ab, WoT, d_out, nullptr, nullptr,
                                                       2048, 2048, 2048, 2);
}

// Round 22
// 134.082 us; speedup vs baseline: 1.0788x; 1.0481x over previous
//
#include <hip/hip_runtime.h>
#include <hip/hip_bf16.h>
#include <math.h>

#define S_LEN 2048
#define HID 2048
#define NH 32
#define NKV 8
#define HD 64
#define WINDOW 1024
#define QBLK 64
#define QKVN 3072   // fused Q(2048) | K(512) | V(512) columns

typedef __attribute__((ext_vector_type(8))) short bx8;          // 8 bf16 (4 VGPRs) — MFMA A/B frag
typedef __attribute__((ext_vector_type(4))) float fx4;          // MFMA C/D frag
typedef __attribute__((ext_vector_type(8))) unsigned short us8; // 8 bf16 raw

#define GL_LDS16(gp, lp) \
    __builtin_amdgcn_global_load_lds((__attribute__((address_space(1))) const void*)(gp), \
                                     (__attribute__((address_space(3))) void*)(lp), 16, 0, 0)

// Packed layouts (swizzle baked in; LDS image identical to previous rounds):
//   A: tile (mt,kt) = 64rows x 32k, elem off = (mt*64+kt)*2048 + r*32 + s*8 + ko,
//      content chunk at slot s is s ^ ((r>>1)&3)
//   B: tile (nt,kt) = 128rows x 32k, elem off = (nt*64+kt)*4096 + r*32 + s*8 + ko

// ---------------- prep: rope tables + hs conv(packed) + weight transposes(packed) ----------------
__global__ __launch_bounds__(256) void prep_kernel(const float* __restrict__ hs,
                                                   const float* __restrict__ Wq,
                                                   const float* __restrict__ Wk,
                                                   const float* __restrict__ Wv,
                                                   const float* __restrict__ Wo,
                                                   float* __restrict__ cosT, float* __restrict__ sinT,
                                                   __hip_bfloat16* __restrict__ hsb,
                                                   __hip_bfloat16* __restrict__ WqkvT,
                                                   __hip_bfloat16* __restrict__ WoT) {
    __shared__ float tile[32][33];
    int b = blockIdx.x, t = threadIdx.x;
    if (b < 256) {
        int idx = b * 256 + t;           // s*32 + f
        int s = idx >> 5, f = idx & 31;
        double inv = exp(-2.0 * (double)f / 64.0 * log(500000.0));
        double ang = (double)s * inv;
        cosT[idx] = (float)cos(ang);
        sinT[idx] = (float)sin(ang);
        return;
    }
    b -= 256;
    if (b < 2048) {
        const int r = t >> 2, sl = t & 3;
        const int mt = b >> 6, kt = b & 63;
        const int chunk = sl ^ ((r >> 1) & 3);
        const float* src = &hs[(size_t)(mt * 64 + r) * 2048 + kt * 32 + chunk * 8];
        float4 a = *reinterpret_cast<const float4*>(src);
        float4 c = *reinterpret_cast<const float4*>(src + 4);
        __hip_bfloat16 o[8] __attribute__((aligned(16)));
        o[0] = __float2bfloat16(a.x); o[1] = __float2bfloat16(a.y);
        o[2] = __float2bfloat16(a.z); o[3] = __float2bfloat16(a.w);
        o[4] = __float2bfloat16(c.x); o[5] = __float2bfloat16(c.y);
        o[6] = __float2bfloat16(c.z); o[7] = __float2bfloat16(c.w);
        *reinterpret_cast<bx8*>(&hsb[(size_t)b * 2048 + t * 8]) = *reinterpret_cast<bx8*>(o);
        return;
    }
    b -= 2048;
    const float* src; __hip_bfloat16* dst; int Nd, bx, by, gbase;
    if (b < 4096)      { src = Wq; dst = WqkvT; Nd = 2048; bx = b & 63; by = b >> 6; gbase = 0; }
    else if (b < 5120) { b -= 4096; src = Wk; dst = WqkvT; Nd = 512; bx = b & 15; by = b >> 4; gbase = 2048; }
    else if (b < 6144) { b -= 5120; src = Wv; dst = WqkvT; Nd = 512; bx = b & 15; by = b >> 4; gbase = 2560; }
    else               { b -= 6144; src = Wo; dst = WoT;   Nd = 2048; bx = b & 63; by = b >> 6; gbase = 0; }
    int n0 = bx * 32, k0 = by * 32, tx = t & 31, ty = t >> 5;  // 32 x 8
#pragma unroll
    for (int i = 0; i < 4; i++)
        tile[ty + 8 * i][tx] = src[(size_t)(k0 + ty + 8 * i) * Nd + n0 + tx];
    __syncthreads();
    const int kt = k0 >> 5, chunk = tx >> 3, ko = tx & 7;
#pragma unroll
    for (int i = 0; i < 4; i++) {
        int gn = gbase + n0 + ty + 8 * i;
        int nt = gn >> 7, r = gn & 127;
        int s2 = chunk ^ ((r >> 1) & 3);
        dst[(size_t)(nt * 64 + kt) * 4096 + r * 32 + s2 * 8 + ko] =
            __float2bfloat16(tile[tx][ty + 8 * i]);
    }
}

// ---------------- V transpose only (RoPE fused into the QKV GEMM epilogue) ----------------
__global__ __launch_bounds__(256) void vtrans_kernel(const __hip_bfloat16* __restrict__ QKV,
                                                     __hip_bfloat16* __restrict__ Vt) {
    __shared__ __hip_bfloat16 tile[32][33];
    int b = blockIdx.x, t = threadIdx.x;
    int s0 = (b & 63) * 32, d0 = (b >> 6) * 32;
    int tx = t & 31, ty = t >> 5;  // 32 x 8
#pragma unroll
    for (int i = 0; i < 4; i++)
        tile[ty + 8 * i][tx] = QKV[(size_t)(s0 + ty + 8 * i) * QKVN + 2560 + d0 + tx];
    __syncthreads();
#pragma unroll
    for (int i = 0; i < 4; i++)
        Vt[(size_t)(d0 + ty + 8 * i) * S_LEN + s0 + tx] = tile[tx][ty + 8 * i];
}

// ---------------- pipelined bf16 MFMA GEMM, 64x128 tile, XCD N-striped (frozen R21) ----------------
template <int APACKED, int OUTBF16, int ROPE>
__global__ __launch_bounds__(256) void gemm_pipe_kernel(const __hip_bfloat16* __restrict__ A,
                                                        const __hip_bfloat16* __restrict__ Bpk,
                                                        void* __restrict__ Cp,
                                                        const float* __restrict__ cosT,
                                                        const float* __restrict__ sinT,
                                                        int M, int N, int K, int stripe) {
    __shared__ __hip_bfloat16 As[4][2048];   // 4 x [64 rows][32 k]
    __shared__ __hip_bfloat16 Bs[4][4096];   // 4 x [128 rows][32 k]

    const int bid = blockIdx.x;
    const int x = bid & 7, j = bid >> 3;
    const int bn = (x * stripe + j % stripe) * 128;
    const int bm = (j / stripe) * 64;

    const int t = threadIdx.x, w = t >> 6, l = t & 63;
    const int wr = (w >> 1) * 32, wc = (w & 1) * 64;
    const int lr = l & 15;
    const int rdslot = (((l >> 4) ^ ((lr >> 1) & 3))) * 8;
    const int srow = w * 16 + (l >> 2);
    const int scol = (((l & 3) ^ ((l >> 3) & 3))) * 8;
    const int ldsoff = w * 512;

    const __hip_bfloat16* ga0 = APACKED
        ? A + (size_t)(bm >> 6) * 131072 + t * 8
        : A + (size_t)(bm + srow) * K + scol;
    const __hip_bfloat16* gb0 = Bpk + (size_t)(bn >> 7) * 262144 + t * 8;

    fx4 acc[2][4];
#pragma unroll
    for (int m = 0; m < 2; m++)
#pragma unroll
        for (int n = 0; n < 4; n++) acc[m][n] = (fx4){0.f, 0.f, 0.f, 0.f};

    const int T = K >> 5;

#define STAGE(kt, b)                                                      \
    do {                                                                  \
        const __hip_bfloat16* ga = APACKED ? ga0 + (kt) * 2048            \
                                           : ga0 + (kt) * 32;             \
        const __hip_bfloat16* gb = gb0 + (kt) * 4096;                     \
        GL_LDS16(ga,        &As[(b)][ldsoff]);                            \
        GL_LDS16(gb,        &Bs[(b)][ldsoff]);                            \
        GL_LDS16(gb + 2048, &Bs[(b)][2048 + ldsoff]);                     \
    } while (0)

    STAGE(0, 0);
    STAGE(1, 1);
    STAGE(2, 2);

    for (int i = 0; i < T; i++) {
        const int r = i & 3;
        if (i + 2 < T)      asm volatile("s_waitcnt vmcnt(6)" ::: "memory");
        else if (i + 1 < T) asm volatile("s_waitcnt vmcnt(3)" ::: "memory");
        else                asm volatile("s_waitcnt vmcnt(0)" ::: "memory");
        __builtin_amdgcn_s_barrier();
        asm volatile("" ::: "memory");
        if (i + 3 < T) STAGE(i + 3, (i + 3) & 3);

        bx8 af[2], bf[4];
#pragma unroll
        for (int m = 0; m < 2; m++)
            af[m] = *reinterpret_cast<const bx8*>(&As[r][(wr + m * 16 + lr) * 32 + rdslot]);
#pragma unroll
        for (int n = 0; n < 4; n++)
            bf[n] = *reinterpret_cast<const bx8*>(&Bs[r][(wc + n * 16 + lr) * 32 + rdslot]);
#pragma unroll
        for (int m = 0; m < 2; m++)
#pragma unroll
            for (int n = 0; n < 4; n++)
                acc[m][n] = __builtin_amdgcn_mfma_f32_16x16x32_bf16(af[m], bf[n], acc[m][n], 0, 0, 0);
    }
#undef STAGE

    const int lq = (l >> 4) * 4;
    const bool doRope = ROPE && (bn + wc) < 2560;   // Q or K head (V skips)
#pragma unroll
    for (int m = 0; m < 2; m++)
#pragma unroll
        for (int r2 = 0; r2 < 4; r2++) {
            const int row = bm + wr + m * 16 + lq + r2;
            float v0 = acc[m][0][r2], v1 = acc[m][1][r2];
            float v2 = acc[m][2][r2], v3 = acc[m][3][r2];
            if (doRope) {
                float c0 = cosT[(row << 5) + lr],      s0 = sinT[(row << 5) + lr];
                float c1 = cosT[(row << 5) + 16 + lr], s1 = sinT[(row << 5) + 16 + lr];
                float o0 = v0 * c0 - v2 * s0, o2 = v2 * c0 + v0 * s0;
                float o1 = v1 * c1 - v3 * s1, o3 = v3 * c1 + v1 * s1;
                v0 = o0; v1 = o1; v2 = o2; v3 = o3;
            }
            float vv[4] = {v0, v1, v2, v3};
#pragma unroll
            for (int n = 0; n < 4; n++) {
                int col = bn + wc + 16 * n + lr;
                if (OUTBF16)
                    ((__hip_bfloat16*)Cp)[(size_t)row * N + col] = __float2bfloat16(vv[n]);
                else
                    ((float*)Cp)[(size_t)row * N + col] = vv[n];
            }
        }
}

// ---------------- MFMA sliding-window flash attention, swapped-operand softmax ----------------
// R22: QBLK=64, 4 waves/block, 1024 blocks. LPT dispatch (qi descending) for
// load balance; head = 4*xcd + j&3 so each XCD serves one kv-head (L2-resident).
// Per-wave 16-row compute path byte-identical to R17/R21.
__global__ __launch_bounds__(256, 4) void attn_kernel(const __hip_bfloat16* __restrict__ Q,
                                                      const __hip_bfloat16* __restrict__ Kg,
                                                      const __hip_bfloat16* __restrict__ Vtg,
                                                      __hip_bfloat16* __restrict__ Ab) {
    __shared__ __hip_bfloat16 Ks[2][4096];
    __shared__ __hip_bfloat16 Vs[2][4096];
    __shared__ __hip_bfloat16 Ps[QBLK * 64];   // 8KB

    // LPT + XCD mapping: xcd = bid&7, j = bid>>3; head = 4*xcd + (j&3);
    // qi = 31 - (j>>2)  (heavy q-tiles dispatched first)
    const int bid = blockIdx.x;
    const int xcd = bid & 7, j = bid >> 3;
    const int h = 4 * xcd + (j & 3);
    const int qi = 31 - (j >> 2);
    const int qb = qi * QBLK;
    const int kvh = h >> 2;

    const int t = threadIdx.x, w = t >> 6, l = t & 63;
    const int lr = l & 15, g = l >> 4, lk = g * 8;
    const int qbw = qb + 16 * w;      // this wave's 16 q-rows
    const int prow = 16 * w + lr;     // this lane's q-row in Ps (0..63)
    const int psz = (prow & 7) << 4;

    char* PsB = (char*)Ps;

    bx8 qa[2];
#pragma unroll
    for (int ks = 0; ks < 2; ks++)
        qa[ks] = *reinterpret_cast<const bx8*>(
            &Q[(size_t)(qbw + lr) * QKVN + h * HD + ks * 32 + lk]);

    fx4 ot[4];
#pragma unroll
    for (int n = 0; n < 4; n++) ot[n] = (fx4){0.f, 0.f, 0.f, 0.f};
    float mrow = -1e30f, srow = 0.f;

    const int k0_first = (qb >= 1024) ? (qb - 1024) : 0;
    const int k0_last  = qb;          // last tile containing row qb+63
    const int wmax = qbw + 15;
    const int wlow = qbw - (WINDOW - 1);
    const int rowq = qbw + lr;

    // staging: 256 threads, 2 ops per buffer. op o covers rows o*32 + w*8 + (l>>3),
    // chunk c8 = l&7; (sr+32)&7 == sr&7 so the swizzled source col is shared.
    const int sr0 = w * 8 + (l >> 3), c8 = l & 7;
    const int scolsw = 8 * (c8 ^ (sr0 & 7));
    const int kcol = kvh * HD + scolsw;
    __hip_bfloat16* ldsK = &Ks[0][0] + w * 512;   // wave-uniform bases
    __hip_bfloat16* ldsV = &Vs[0][0] + w * 512;

#define ASTAGE(k0v, p)                                                                  \
    do {                                                                                \
        GL_LDS16(&Kg[(size_t)((k0v) + sr0) * QKVN + kcol],       ldsK + (p) * 4096);    \
        GL_LDS16(&Kg[(size_t)((k0v) + sr0 + 32) * QKVN + kcol],  ldsK + (p) * 4096 + 2048); \
        GL_LDS16(&Vtg[(size_t)(kvh * HD + sr0) * S_LEN + (k0v) + scolsw],               \
                 ldsV + (p) * 4096);                                                    \
        GL_LDS16(&Vtg[(size_t)(kvh * HD + sr0 + 32) * S_LEN + (k0v) + scolsw],          \
                 ldsV + (p) * 4096 + 2048);                                             \
    } while (0)

    ASTAGE(k0_first, 0);

    int ti = 0;
    for (int k0 = k0_first; k0 <= k0_last; k0 += 64, ++ti) {
        const int p = ti & 1;
        asm volatile("s_waitcnt vmcnt(0)" ::: "memory");
        __builtin_amdgcn_s_barrier();
        asm volatile("" ::: "memory");
        if (k0 + 64 <= k0_last) ASTAGE(k0 + 64, p ^ 1);

        if (k0 <= wmax && k0 + 63 >= wlow) {
            char* KsB = (char*)&Ks[p][0];
            char* VsB = (char*)&Vs[p][0];
            bx8 kb[4][2];
#pragma unroll
            for (int n = 0; n < 4; n++)
#pragma unroll
                for (int ks = 0; ks < 2; ks++) {
                    int row = 16 * n + lr;
                    kb[n][ks] = *reinterpret_cast<const bx8*>(
                        KsB + row * 128 + (((ks * 64) + 16 * g) ^ ((row & 7) << 4)));
                }
            fx4 sc[4];
#pragma unroll
            for (int n = 0; n < 4; n++) {
                sc[n] = __builtin_amdgcn_mfma_f32_16x16x32_bf16(kb[n][0], qa[0],
                                                                (fx4){0.f, 0.f, 0.f, 0.f}, 0, 0, 0);
                sc[n] = __builtin_amdgcn_mfma_f32_16x16x32_bf16(kb[n][1], qa[1], sc[n], 0, 0, 0);
            }
            const bool interior = (k0 + 63 <= qbw) && (k0 >= qbw - 1008);
            if (interior) {
#pragma unroll
                for (int n = 0; n < 4; n++)
#pragma unroll
                    for (int r = 0; r < 4; r++) sc[n][r] *= 0.125f;
            } else {
#pragma unroll
                for (int n = 0; n < 4; n++)
#pragma unroll
                    for (int r = 0; r < 4; r++) {
                        int key = k0 + 16 * n + 4 * g + r;
                        bool valid = (key <= rowq) && (key >= rowq - (WINDOW - 1));
                        sc[n][r] = valid ? sc[n][r] * 0.125f : -1e30f;
                    }
            }
            float tmax = fmaxf(fmaxf(sc[0][0], sc[0][1]), fmaxf(sc[0][2], sc[0][3]));
#pragma unroll
            for (int n = 1; n < 4; n++)
                tmax = fmaxf(tmax, fmaxf(fmaxf(sc[n][0], sc[n][1]), fmaxf(sc[n][2], sc[n][3])));
            tmax = fmaxf(tmax, __shfl_xor(tmax, 16));
            tmax = fmaxf(tmax, __shfl_xor(tmax, 32));
            const bool grew = __any(tmax > mrow);
            float mn = mrow, fs = 1.f;
            if (grew) {
                mn = fmaxf(mrow, tmax);
                fs = __expf(mrow - mn);
                mrow = mn;
            }
            float ps = 0.f;
#pragma unroll
            for (int n = 0; n < 4; n++) {
#pragma unroll
                for (int r = 0; r < 4; r++) {
                    float p2 = __expf(sc[n][r] - mn);
                    sc[n][r] = p2;
                    ps += p2;
                }
                __hip_bfloat16 pk[4] __attribute__((aligned(8)));
                pk[0] = __float2bfloat16(sc[n][0]); pk[1] = __float2bfloat16(sc[n][1]);
                pk[2] = __float2bfloat16(sc[n][2]); pk[3] = __float2bfloat16(sc[n][3]);
                *reinterpret_cast<unsigned long long*>(PsB + prow * 128 + ((32 * n + 8 * g) ^ psz)) =
                    *reinterpret_cast<unsigned long long*>(pk);
            }
            ps += __shfl_xor(ps, 16);
            ps += __shfl_xor(ps, 32);
            if (grew) {
                srow = srow * fs + ps;
#pragma unroll
                for (int n = 0; n < 4; n++)
#pragma unroll
                    for (int r = 0; r < 4; r++) ot[n][r] *= fs;
            } else {
                srow += ps;
            }
            bx8 vb[4][2];
#pragma unroll
            for (int n = 0; n < 4; n++)
#pragma unroll
                for (int ks = 0; ks < 2; ks++) {
                    int row = 16 * n + lr;
                    vb[n][ks] = *reinterpret_cast<const bx8*>(
                        VsB + row * 128 + (((ks * 64) + 16 * g) ^ ((row & 7) << 4)));
                }
            bx8 pb[2];
#pragma unroll
            for (int ks = 0; ks < 2; ks++)
                pb[ks] = *reinterpret_cast<const bx8*>(
                    PsB + prow * 128 + (((ks * 64) + 16 * g) ^ psz));
#pragma unroll
            for (int n = 0; n < 4; n++) {
                ot[n] = __builtin_amdgcn_mfma_f32_16x16x32_bf16(vb[n][0], pb[0], ot[n], 0, 0, 0);
                ot[n] = __builtin_amdgcn_mfma_f32_16x16x32_bf16(vb[n][1], pb[1], ot[n], 0, 0, 0);
            }
        }
    }
#undef ASTAGE

    // ---- epilogue: normalize, O^T frags -> Ps as [q][d], then PACKED-A write ----
    const float inv = 1.f / srow;
#pragma unroll
    for (int n = 0; n < 4; n++) {
        __hip_bfloat16 pk[4] __attribute__((aligned(8)));
#pragma unroll
        for (int r = 0; r < 4; r++) pk[r] = __float2bfloat16(ot[n][r] * inv);
        *reinterpret_cast<unsigned long long*>(PsB + prow * 128 + ((32 * n + 8 * g) ^ psz)) =
            *reinterpret_cast<unsigned long long*>(pk);
    }
    __syncthreads();
#pragma unroll
    for (int j2 = 0; j2 < 2; j2++) {
        const int row = (t >> 3) + 32 * j2, c = t & 7;   // 64 rows x 8 us8-chunks
        us8 v = *reinterpret_cast<const us8*>(PsB + row * 128 + ((c * 16) ^ ((row & 7) << 4)));
        const int R = qb + row;
        const int mt = R >> 6, rloc = R & 63;
        const int kt = 2 * h + (c >> 2);
        const int slot = (c & 3) ^ ((rloc >> 1) & 3);
        *reinterpret_cast<us8*>(&Ab[(size_t)(mt * 64 + kt) * 2048 + rloc * 32 + slot * 8]) = v;
    }
}

extern "C" void kernel_launch(void* const* d_in, const int* in_sizes, int n_in,
                              void* d_out, int out_size, void* d_ws, size_t ws_size,
                              hipStream_t stream) {
    const float* hs = (const float*)d_in[0];
    const float* Wq = (const float*)d_in[1];
    const float* Wk = (const float*)d_in[2];
    const float* Wv = (const float*)d_in[3];
    const float* Wo = (const float*)d_in[4];

    float* ws   = (float*)d_ws;
    float* cosT = ws;                  // 65536 f32
    float* sinT = cosT + 65536;        // 65536 f32
    __hip_bfloat16* hsb    = (__hip_bfloat16*)(sinT + 65536);   // [2048][2048] (packed A)
    __hip_bfloat16* WqkvT  = hsb + 4194304;                     // [3072][2048] (packed B)
    __hip_bfloat16* WoT    = WqkvT + 6291456;                   // [2048][2048] (packed B)
    __hip_bfloat16* QKVb   = WoT + 4194304;                     // [2048][3072] row-major
    __hip_bfloat16* Vt     = QKVb + 6291456;                    // [512][2048]
    __hip_bfloat16* Ab     = hsb;                               // alias: packed A for Wo gemm

    // prep: tables + hs->bf16(packed) + weight transposes(packed)
    prep_kernel<<<12544, 256, 0, stream>>>(hs, Wq, Wk, Wv, Wo, cosT, sinT, hsb, WqkvT, WoT);

    // fused QKV projection + RoPE-in-epilogue (A packed, B packed)
    gemm_pipe_kernel<1, 1, 1><<<768, 256, 0, stream>>>(hsb, WqkvT, QKVb, cosT, sinT,
                                                       2048, QKVN, 2048, 3);

    // V transpose only (RoPE done in GEMM)
    vtrans_kernel<<<1024, 256, 0, stream>>>(QKVb, Vt);

    // attention: 1024 blocks (QBLK=64, 4 waves), LPT-ordered, packed-A output
    attn_kernel<<<1024, 256, 0, stream>>>(QKVb, QKVb + 2048, Vt, Ab);

    // output projection (A packed, B packed)
    gemm_pipe_kernel<1, 0, 0><<<512, 256, 0, stream>>>(Ab, WoT, d_out, nullptr, nullptr,
                                                       2048, 2048, 2048, 2);
}